// Round 9
// baseline (192.994 us; speedup 1.0000x reference)
//
#include <hip/hip_runtime.h>
#include <hip/hip_bf16.h>

#define N_NODES 50000
#define N_EDGES 800000
#define F 64    // IN_FEATS == HIDDEN
#define C 32    // NUM_CLASSES
#define CAP 48  // fixed CSR row capacity; in-deg ~Poisson(16), max ~40

#define NPB   800    // partition blocks (3+ waves/SIMD)
#define EPB   1000   // edges per partition block (800*1000 == 800000)
#define NBUCK 196    // node buckets of 256 nodes
#define SEGCAP 5120  // per-bucket edge segment (mean 4096, sd 64 -> 16 sigma)

#define G1_BLOCKS   2048  // persistent blocks for gather64_gemv
#define GOUT_BLOCKS 2048  // persistent blocks for gather_out

static __device__ __forceinline__ float bflo(int u) {
    return __uint_as_float(((unsigned)u) << 16);
}
static __device__ __forceinline__ float bfhi(int u) {
    return __uint_as_float(((unsigned)u) & 0xffff0000u);
}
static __device__ __forceinline__ unsigned short f2bf(float f) {
    __hip_bfloat16 h = __float2bfloat16(f);
    return *reinterpret_cast<unsigned short*>(&h);
}

// Streaming L2 prefill: blocks with blockIdx%8 == x (presumed XCD x) collectively
// stream the whole table into XCD x's L2. Perf heuristic only — if the mapping
// assumption is wrong, uncovered lines just miss as before. `sx` kept live via
// empty asm so the loads aren't DCE'd.
static __device__ __forceinline__ void l2_prefill(const int4* __restrict__ tab,
                                                  int tot_i4, int slice, int t) {
    int per = (tot_i4 + 255) >> 8;     // int4s per slice (256 slices)
    int end = slice * per + per;
    if (end > tot_i4) end = tot_i4;
    int sx = 0;
    for (int i = slice * per + t; i < end; i += 256) {
        int4 v = tab[i];
        sx ^= v.x ^ v.y ^ v.z ^ v.w;
    }
    asm volatile("" :: "v"(sx));
}

// ---- fused partition v2: LDS count -> segment reservation -> scatter --------------
__global__ void part_fused_kernel(const int* __restrict__ src, const int* __restrict__ dst,
                                  int* __restrict__ gseg,        // [2*NBUCK], pre-zeroed
                                  int* __restrict__ edge_d, unsigned char* __restrict__ edge_s) {
    __shared__ int hd[NBUCK], hs[NBUCK];
    int t = threadIdx.x;
    for (int i = t; i < NBUCK; i += 256) { hd[i] = 0; hs[i] = 0; }
    __syncthreads();
    int b0 = blockIdx.x * EPB;
    const int4* s4 = reinterpret_cast<const int4*>(src + b0);
    const int4* d4 = reinterpret_cast<const int4*>(dst + b0);
    // pass 1: per-bucket counts in LDS (dst and src)
    for (int i = t; i < EPB / 4; i += 256) {
        int4 dv = d4[i];
        int4 sv = s4[i];
        atomicAdd(&hd[dv.x >> 8], 1); atomicAdd(&hd[dv.y >> 8], 1);
        atomicAdd(&hd[dv.z >> 8], 1); atomicAdd(&hd[dv.w >> 8], 1);
        atomicAdd(&hs[sv.x >> 8], 1); atomicAdd(&hs[sv.y >> 8], 1);
        atomicAdd(&hs[sv.z >> 8], 1); atomicAdd(&hs[sv.w >> 8], 1);
    }
    __syncthreads();
    // reserve contiguous ranges; hd/hs become absolute cursors
    for (int i = t; i < NBUCK; i += 256) {
        hd[i] = i * SEGCAP + atomicAdd(&gseg[i], hd[i]);
        hs[i] = i * SEGCAP + atomicAdd(&gseg[NBUCK + i], hs[i]);
    }
    __syncthreads();
    // pass 2: scatter (src/dst re-read is an L2 hit; 8KB/block)
    for (int i = t; i < EPB / 4; i += 256) {
        int4 dv = d4[i];
        int4 sv = s4[i];
        int p;
        p = atomicAdd(&hd[dv.x >> 8], 1); edge_d[p] = ((dv.x & 255) << 16) | sv.x;
        p = atomicAdd(&hd[dv.y >> 8], 1); edge_d[p] = ((dv.y & 255) << 16) | sv.y;
        p = atomicAdd(&hd[dv.z >> 8], 1); edge_d[p] = ((dv.z & 255) << 16) | sv.z;
        p = atomicAdd(&hd[dv.w >> 8], 1); edge_d[p] = ((dv.w & 255) << 16) | sv.w;
        p = atomicAdd(&hs[sv.x >> 8], 1); edge_s[p] = (unsigned char)(sv.x & 255);
        p = atomicAdd(&hs[sv.y >> 8], 1); edge_s[p] = (unsigned char)(sv.y & 255);
        p = atomicAdd(&hs[sv.z >> 8], 1); edge_s[p] = (unsigned char)(sv.z & 255);
        p = atomicAdd(&hs[sv.w >> 8], 1); edge_s[p] = (unsigned char)(sv.w & 255);
    }
}

// ---- per-bucket CSR build -> ushort csr + meta{nd,ns,cnt} -------------------------
__global__ void bucket_build_kernel(const int* __restrict__ edge_d,
                                    const unsigned char* __restrict__ edge_s,
                                    const int* __restrict__ gseg,
                                    unsigned short* __restrict__ csr,
                                    float4* __restrict__ meta) {
    __shared__ int cur[256];
    __shared__ int hsm[256];
    int t = threadIdx.x;
    int bucket = blockIdx.x;
    cur[t] = 0;
    hsm[t] = 0;
    __syncthreads();
    int lend = gseg[bucket];           if (lend > SEGCAP) lend = SEGCAP;
    int lens = gseg[NBUCK + bucket];   if (lens > SEGCAP) lens = SEGCAP;
    int lo = bucket * SEGCAP;
    for (int i = lo + t; i < lo + lend; i += 256) {
        int pd = edge_d[i];
        int dlow = pd >> 16;
        int s = pd & 0xFFFF;
        int pos = atomicAdd(&cur[dlow], 1);
        if (pos < CAP)
            csr[(size_t)(bucket * 256 + dlow) * CAP + pos] = (unsigned short)s;
    }
    for (int i = lo + t; i < lo + lens; i += 256) {
        atomicAdd(&hsm[edge_s[i]], 1);
    }
    __syncthreads();
    int node = bucket * 256 + t;
    if (node < N_NODES) {
        int c = cur[t] < CAP ? cur[t] : CAP;
        float4 m;
        m.x = rsqrtf(fmaxf((float)c, 1.0f));         // norm_dst
        m.y = rsqrtf(fmaxf((float)hsm[t], 1.0f));    // norm_src
        m.z = __int_as_float(c);                     // cnt
        m.w = 0.f;
        meta[node] = m;
    }
}

// ---------------- y = bf16((x @ W1) * norm_src)  [N x 64] ----------------
__global__ void gemm_y_kernel(const float* __restrict__ x,
                              const float4* __restrict__ meta,
                              const float* __restrict__ W,   // [F][F]
                              __hip_bfloat16* __restrict__ y) {
    __shared__ float sW[F * F];      // 16 KB
    __shared__ float srow[16][F];    // 4 KB
    int t = threadIdx.x;
    for (int i = t; i < F * F; i += 256) sW[i] = W[i];
    int j = t & 63;            // output feature
    int w = t >> 6;            // wave 0..3
    int base = blockIdx.x * 16;
    for (int r = w; r < 16; r += 4) srow[r][j] = x[(size_t)(base + r) * F + j];
    __syncthreads();
    float a0 = 0, a1 = 0, a2 = 0, a3 = 0;
#pragma unroll
    for (int k = 0; k < F; k++) {
        float wv = sW[k * F + j];
        a0 += srow[w * 4 + 0][k] * wv;
        a1 += srow[w * 4 + 1][k] * wv;
        a2 += srow[w * 4 + 2][k] * wv;
        a3 += srow[w * 4 + 3][k] * wv;
    }
    int n0 = base + w * 4;
    y[(size_t)(n0 + 0) * F + j] = __float2bfloat16(a0 * meta[n0 + 0].y);
    y[(size_t)(n0 + 1) * F + j] = __float2bfloat16(a1 * meta[n0 + 1].y);
    y[(size_t)(n0 + 2) * F + j] = __float2bfloat16(a2 * meta[n0 + 2].y);
    y[(size_t)(n0 + 3) * F + j] = __float2bfloat16(a3 * meta[n0 + 3].y);
}

// -------- gather64 + fused W2 GEMV (v7): v6 + streaming L2 prefill of y ------------
__global__ void gather64_gemv_kernel(const __hip_bfloat16* __restrict__ y,
                                     const unsigned short* __restrict__ csr,
                                     const float4* __restrict__ meta,
                                     const float* __restrict__ b1,
                                     const float* __restrict__ W2,  // [F][C]
                                     __hip_bfloat16* __restrict__ gt) {  // [N][32]
    __shared__ float sW[F * C];       // 8 KB
    int t = threadIdx.x;
    for (int i = t; i < F * C; i += 256) sW[i] = W2[i];
    const unsigned short* ytab = reinterpret_cast<const unsigned short*>(y);
    // stream this XCD's copy of y into L2 (6.4 MB table; partial residency in 4 MB)
    l2_prefill(reinterpret_cast<const int4*>(ytab), N_NODES * F * 2 / 16,
               blockIdx.x >> 3, t);
    __syncthreads();                  // only barrier in the kernel
    int w    = t >> 6;
    int lane = t & 63;
    int g  = lane >> 3;               // edge group 0..7
    int fo = (lane & 7) * 8;          // feature offset (8 feats/lane)
    int j    = lane & 31;             // GEMV output class
    int half = lane >> 5;             // GEMV k-half
    const float4 b1a = *reinterpret_cast<const float4*>(b1 + fo);
    const float4 b1b = *reinterpret_cast<const float4*>(b1 + fo + 4);
    const int STRIDE = G1_BLOCKS * 4;

    int node = blockIdx.x * 4 + w;
    float4 pm = meta[node];
    const unsigned short* prow = csr + (size_t)node * CAP;
    int pr0 = prow[g], pr1 = prow[8 + g], pr2 = prow[16 + g];

    while (node < N_NODES) {
        float nd = pm.x, ns = pm.y;
        int n = __float_as_int(pm.z);
        int r0 = pr0, r1 = pr1, r2 = pr2;
        int nxt = node + STRIDE;
        int pf = (nxt < N_NODES) ? nxt : node;   // clamp (harmless refetch)

        int ss0 = (g      < n) ? r0 : 0;  float m0 = (g      < n) ? 1.f : 0.f;
        int ss1 = (8  + g < n) ? r1 : 0;  float m1 = (8  + g < n) ? 1.f : 0.f;
        int ss2 = (16 + g < n) ? r2 : 0;  float m2 = (16 + g < n) ? 1.f : 0.f;

        const int4 v0 = *reinterpret_cast<const int4*>(ytab + (size_t)ss0 * F + fo);
        const int4 v1 = *reinterpret_cast<const int4*>(ytab + (size_t)ss1 * F + fo);
        const int4 v2 = *reinterpret_cast<const int4*>(ytab + (size_t)ss2 * F + fo);

        // prefetch next node's meta + row indices (overlaps y epoch)
        pm = meta[pf];
        const unsigned short* nrow = csr + (size_t)pf * CAP;
        pr0 = nrow[g]; pr1 = nrow[8 + g]; pr2 = nrow[16 + g];

        float a0, a1, a2, a3, a4, a5, a6, a7;
        a0 = m0 * bflo(v0.x); a1 = m0 * bfhi(v0.x);
        a2 = m0 * bflo(v0.y); a3 = m0 * bfhi(v0.y);
        a4 = m0 * bflo(v0.z); a5 = m0 * bfhi(v0.z);
        a6 = m0 * bflo(v0.w); a7 = m0 * bfhi(v0.w);

#define G1_ACC(vv, mm)                                                        \
        a0 = fmaf(mm, bflo(vv.x), a0); a1 = fmaf(mm, bfhi(vv.x), a1);         \
        a2 = fmaf(mm, bflo(vv.y), a2); a3 = fmaf(mm, bfhi(vv.y), a3);         \
        a4 = fmaf(mm, bflo(vv.z), a4); a5 = fmaf(mm, bfhi(vv.z), a5);         \
        a6 = fmaf(mm, bflo(vv.w), a6); a7 = fmaf(mm, bfhi(vv.w), a7);
        G1_ACC(v1, m1)
        G1_ACC(v2, m2)

        if (__builtin_expect(n > 24, 0)) {   // wave-uniform, ~2% of nodes
            const unsigned short* row = csr + (size_t)node * CAP;
            int r3 = row[24 + g], r4 = row[32 + g], r5 = row[40 + g];
            int ss3 = (24 + g < n) ? r3 : 0;  float m3 = (24 + g < n) ? 1.f : 0.f;
            int ss4 = (32 + g < n) ? r4 : 0;  float m4 = (32 + g < n) ? 1.f : 0.f;
            int ss5 = (40 + g < n) ? r5 : 0;  float m5 = (40 + g < n) ? 1.f : 0.f;
            const int4 v3 = *reinterpret_cast<const int4*>(ytab + (size_t)ss3 * F + fo);
            const int4 v4 = *reinterpret_cast<const int4*>(ytab + (size_t)ss4 * F + fo);
            const int4 v5 = *reinterpret_cast<const int4*>(ytab + (size_t)ss5 * F + fo);
            G1_ACC(v3, m3)
            G1_ACC(v4, m4)
            G1_ACC(v5, m5)
        }
#undef G1_ACC

        // butterfly over the 8 edge groups -> every lane holds full h[fo..fo+7]
#define G1_RED(mk)                                                           \
        a0 += __shfl_xor(a0, mk); a1 += __shfl_xor(a1, mk);                  \
        a2 += __shfl_xor(a2, mk); a3 += __shfl_xor(a3, mk);                  \
        a4 += __shfl_xor(a4, mk); a5 += __shfl_xor(a5, mk);                  \
        a6 += __shfl_xor(a6, mk); a7 += __shfl_xor(a7, mk);
        G1_RED(8)
        G1_RED(16)
        G1_RED(32)
#undef G1_RED

        float hh[8];
        hh[0] = fmaxf(fmaf(a0, nd, b1a.x), 0.f) * ns;
        hh[1] = fmaxf(fmaf(a1, nd, b1a.y), 0.f) * ns;
        hh[2] = fmaxf(fmaf(a2, nd, b1a.z), 0.f) * ns;
        hh[3] = fmaxf(fmaf(a3, nd, b1a.w), 0.f) * ns;
        hh[4] = fmaxf(fmaf(a4, nd, b1b.x), 0.f) * ns;
        hh[5] = fmaxf(fmaf(a5, nd, b1b.y), 0.f) * ns;
        hh[6] = fmaxf(fmaf(a6, nd, b1b.z), 0.f) * ns;
        hh[7] = fmaxf(fmaf(a7, nd, b1b.w), 0.f) * ns;

        // GEMV: o_j = sum_k h[kk] * W2[kk][j]; h[kk] lives at lane kk>>3, comp kk&7
        float o = 0.f;
#pragma unroll
        for (int k = 0; k < 32; k++) {
            float hv = __shfl(hh[k & 7], (half << 2) + (k >> 3));
            o = fmaf(hv, sW[(half * 32 + k) * C + j], o);
        }
        o += __shfl_down(o, 32);
        if (half == 0)
            __builtin_nontemporal_store(f2bf(o),
                reinterpret_cast<unsigned short*>(gt) + (size_t)node * C + j);
        node = nxt;
    }
}

// -------- gather_out (v7): v6 + streaming L2 prefill of gt (3.2 MB fits L2) --------
__global__ void gather_out_kernel(const __hip_bfloat16* __restrict__ gt,  // [N][32]
                                  const unsigned short* __restrict__ csr,
                                  const float4* __restrict__ meta,
                                  const float* __restrict__ b2,
                                  float* __restrict__ out) {
    int t = threadIdx.x;
    const unsigned short* tab = reinterpret_cast<const unsigned short*>(gt);
    // stream this XCD's copy of gt into L2 (3.2 MB — fits the 4 MB per-XCD L2)
    l2_prefill(reinterpret_cast<const int4*>(tab), N_NODES * C * 2 / 16,
               blockIdx.x >> 3, t);
    int w = t >> 6;
    int lane = t & 63;
    int g  = lane >> 3;                     // edge group 0..7
    int fo = (lane & 7) * 4;                // feature offset (4 feats/lane)
    const float4 bb = *reinterpret_cast<const float4*>(b2 + fo);
    const int STRIDE = GOUT_BLOCKS * 4;

    int node = blockIdx.x * 4 + w;
    float4 pm = meta[node];
    const unsigned short* prow = csr + (size_t)node * CAP;
    int pr0 = prow[g], pr1 = prow[8 + g], pr2 = prow[16 + g];

    while (node < N_NODES) {
        float nd = pm.x;
        int n = __float_as_int(pm.z);
        int r0 = pr0, r1 = pr1, r2 = pr2;
        int nxt = node + STRIDE;
        int pf = (nxt < N_NODES) ? nxt : node;

        int ss0 = (g      < n) ? r0 : 0;  float m0 = (g      < n) ? 1.f : 0.f;
        int ss1 = (8  + g < n) ? r1 : 0;  float m1 = (8  + g < n) ? 1.f : 0.f;
        int ss2 = (16 + g < n) ? r2 : 0;  float m2 = (16 + g < n) ? 1.f : 0.f;

        const int2 v0 = *reinterpret_cast<const int2*>(tab + (size_t)ss0 * C + fo);
        const int2 v1 = *reinterpret_cast<const int2*>(tab + (size_t)ss1 * C + fo);
        const int2 v2 = *reinterpret_cast<const int2*>(tab + (size_t)ss2 * C + fo);

        pm = meta[pf];
        const unsigned short* nrow = csr + (size_t)pf * CAP;
        pr0 = nrow[g]; pr1 = nrow[8 + g]; pr2 = nrow[16 + g];

        float a0, a1, a2, a3;
        a0 = m0 * bflo(v0.x); a1 = m0 * bfhi(v0.x);
        a2 = m0 * bflo(v0.y); a3 = m0 * bfhi(v0.y);

#define G2_ACC(vv, mm)                                                        \
        a0 = fmaf(mm, bflo(vv.x), a0); a1 = fmaf(mm, bfhi(vv.x), a1);         \
        a2 = fmaf(mm, bflo(vv.y), a2); a3 = fmaf(mm, bfhi(vv.y), a3);
        G2_ACC(v1, m1)
        G2_ACC(v2, m2)

        if (__builtin_expect(n > 24, 0)) {   // wave-uniform, ~2% of nodes
            const unsigned short* row = csr + (size_t)node * CAP;
            int r3 = row[24 + g], r4 = row[32 + g], r5 = row[40 + g];
            int ss3 = (24 + g < n) ? r3 : 0;  float m3 = (24 + g < n) ? 1.f : 0.f;
            int ss4 = (32 + g < n) ? r4 : 0;  float m4 = (32 + g < n) ? 1.f : 0.f;
            int ss5 = (40 + g < n) ? r5 : 0;  float m5 = (40 + g < n) ? 1.f : 0.f;
            const int2 v3 = *reinterpret_cast<const int2*>(tab + (size_t)ss3 * C + fo);
            const int2 v4 = *reinterpret_cast<const int2*>(tab + (size_t)ss4 * C + fo);
            const int2 v5 = *reinterpret_cast<const int2*>(tab + (size_t)ss5 * C + fo);
            G2_ACC(v3, m3)
            G2_ACC(v4, m4)
            G2_ACC(v5, m5)
        }
#undef G2_ACC

        a0 += __shfl_xor(a0, 8);  a1 += __shfl_xor(a1, 8);
        a2 += __shfl_xor(a2, 8);  a3 += __shfl_xor(a3, 8);
        a0 += __shfl_xor(a0, 16); a1 += __shfl_xor(a1, 16);
        a2 += __shfl_xor(a2, 16); a3 += __shfl_xor(a3, 16);
        a0 += __shfl_xor(a0, 32); a1 += __shfl_xor(a1, 32);
        a2 += __shfl_xor(a2, 32); a3 += __shfl_xor(a3, 32);

        if (lane < 8) {
            float o0 = fmaf(a0, nd, bb.x);
            float o1 = fmaf(a1, nd, bb.y);
            float o2 = fmaf(a2, nd, bb.z);
            float o3 = fmaf(a3, nd, bb.w);
            unsigned long long p0 = ((unsigned long long)__float_as_uint(o0)) |
                                    ((unsigned long long)__float_as_uint(o1) << 32);
            unsigned long long p1 = ((unsigned long long)__float_as_uint(o2)) |
                                    ((unsigned long long)__float_as_uint(o3) << 32);
            unsigned long long* po = reinterpret_cast<unsigned long long*>(
                out + (size_t)node * C + fo);
            __builtin_nontemporal_store(p0, po);
            __builtin_nontemporal_store(p1, po + 1);
        }
        node = nxt;
    }
}

extern "C" void kernel_launch(void* const* d_in, const int* in_sizes, int n_in,
                              void* d_out, int out_size, void* d_ws, size_t ws_size,
                              hipStream_t stream) {
    const float* features = (const float*)d_in[0];   // [N, 64]
    const int*   src      = (const int*)d_in[1];     // [E]
    const int*   dst      = (const int*)d_in[2];     // [E]
    const float* W1       = (const float*)d_in[3];   // [64,64]
    const float* b1       = (const float*)d_in[4];   // [64]
    const float* W2       = (const float*)d_in[5];   // [64,32]
    const float* b2       = (const float*)d_in[6];   // [32]
    float* out = (float*)d_out;                      // [N, 32]

    // ---- workspace layout ----
    //   meta[N]float4 (0.8 MB) | csr[N*CAP]ushort (4.8 MB) | y[N*F]bf16 (6.4 MB) |
    //   gt[N*C]bf16 (3.2 MB)
    // aliases: edge_d (4.01 MB) + edge_s (0.98 MB) in y region (dead before gemm_y
    //          writes y); gseg[392] (1.6 KB) in gt region (dead after bucket_build).
    char* p = (char*)d_ws;
    float4* meta = (float4*)p;            p += (size_t)N_NODES * 16;       // 0.8 MB
    unsigned short* csr = (unsigned short*)p; p += (size_t)N_NODES * CAP * 2; // 4.8 MB
    __hip_bfloat16* y  = (__hip_bfloat16*)p;  p += (size_t)N_NODES * F * 2; // 6.4 MB
    __hip_bfloat16* gt = (__hip_bfloat16*)p;  /* 3.2 MB */

    int* edge_d = (int*)y;                                     // 4.01 MB
    unsigned char* edge_s = (unsigned char*)(edge_d + NBUCK * SEGCAP); // 0.98 MB
    int* gseg   = (int*)gt;                                    // 1.6 KB

    // 0) zero gseg cursors (tiny, graph-capture-safe)
    hipMemsetAsync(gseg, 0, (size_t)(2 * NBUCK) * 4, stream);

    // 1) graph build: fused count+reserve+scatter, then per-bucket CSR build
    part_fused_kernel<<<NPB, 256, 0, stream>>>(src, dst, gseg, edge_d, edge_s);
    bucket_build_kernel<<<NBUCK, 256, 0, stream>>>(edge_d, edge_s, gseg, csr, meta);

    // 2) layer 1 + fused W2 GEMV -> gt (3.2 MB, L2-resident)
    gemm_y_kernel<<<N_NODES / 16, 256, 0, stream>>>(features, meta, W1, y);
    gather64_gemv_kernel<<<G1_BLOCKS, 256, 0, stream>>>(y, csr, meta, b1, W2, gt);

    // 3) layer 2: small-row gather + epilogue (prefilled, pipelined, persistent)
    gather_out_kernel<<<GOUT_BLOCKS, 256, 0, stream>>>(gt, csr, meta, b2, out);
}

// Round 10
// 189.884 us; speedup vs baseline: 1.0164x; 1.0164x over previous
//
#include <hip/hip_runtime.h>
#include <hip/hip_bf16.h>

#define N_NODES 50000
#define N_EDGES 800000
#define F 64    // IN_FEATS == HIDDEN
#define C 32    // NUM_CLASSES
#define CAP 48  // fixed CSR row capacity; in-deg ~Poisson(16), max ~40

#define NPB   800    // partition blocks (3+ waves/SIMD)
#define EPB   1000   // edges per partition block (800*1000 == 800000)
#define NBUCK 196    // node buckets of 256 nodes
#define SEGCAP 5120  // per-bucket edge segment (mean 4096, sd 64 -> 16 sigma)

#define G1_BLOCKS   2048  // persistent blocks for gather64_gemv
#define GOUT_BLOCKS 2048  // persistent blocks for gather_out
#define GY_BLOCKS   2048  // persistent blocks for gemm_y

static __device__ __forceinline__ float bflo(int u) {
    return __uint_as_float(((unsigned)u) << 16);
}
static __device__ __forceinline__ float bfhi(int u) {
    return __uint_as_float(((unsigned)u) & 0xffff0000u);
}
static __device__ __forceinline__ unsigned short f2bf(float f) {
    __hip_bfloat16 h = __float2bfloat16(f);
    return *reinterpret_cast<unsigned short*>(&h);
}

// ---- fused partition v3: PER-WAVE histograms + cursors ----------------------------
// R8's version had 4 waves hammering one shared hd[196]/hs[196] with LDS atomics
// in both passes (3.2M total) -> cross-wave same-address serialization. v3 gives
// each wave private counters (6.3 KB LDS); reservation composes per-wave bases.
// Each wave scatters exactly the edges it counted (same t-indexed strided loop).
__global__ void part_fused_kernel(const int* __restrict__ src, const int* __restrict__ dst,
                                  int* __restrict__ gseg,        // [2*NBUCK], pre-zeroed
                                  int* __restrict__ edge_d, unsigned char* __restrict__ edge_s) {
    __shared__ int hd[4][NBUCK], hs[4][NBUCK];
    int t = threadIdx.x;
    int w = t >> 6;
    for (int i = t; i < 4 * NBUCK; i += 256) {
        (&hd[0][0])[i] = 0;
        (&hs[0][0])[i] = 0;
    }
    __syncthreads();
    int b0 = blockIdx.x * EPB;
    const int4* s4 = reinterpret_cast<const int4*>(src + b0);
    const int4* d4 = reinterpret_cast<const int4*>(dst + b0);
    // pass 1: per-wave bucket counts
    for (int i = t; i < EPB / 4; i += 256) {
        int4 dv = d4[i];
        int4 sv = s4[i];
        atomicAdd(&hd[w][dv.x >> 8], 1); atomicAdd(&hd[w][dv.y >> 8], 1);
        atomicAdd(&hd[w][dv.z >> 8], 1); atomicAdd(&hd[w][dv.w >> 8], 1);
        atomicAdd(&hs[w][sv.x >> 8], 1); atomicAdd(&hs[w][sv.y >> 8], 1);
        atomicAdd(&hs[w][sv.z >> 8], 1); atomicAdd(&hs[w][sv.w >> 8], 1);
    }
    __syncthreads();
    // reserve contiguous ranges; arrays become per-wave absolute cursors
    if (t < NBUCK) {
        int c0 = hd[0][t], c1 = hd[1][t], c2 = hd[2][t], c3 = hd[3][t];
        int base = t * SEGCAP + atomicAdd(&gseg[t], c0 + c1 + c2 + c3);
        hd[0][t] = base;
        hd[1][t] = base + c0;
        hd[2][t] = base + c0 + c1;
        hd[3][t] = base + c0 + c1 + c2;
        c0 = hs[0][t]; c1 = hs[1][t]; c2 = hs[2][t]; c3 = hs[3][t];
        base = t * SEGCAP + atomicAdd(&gseg[NBUCK + t], c0 + c1 + c2 + c3);
        hs[0][t] = base;
        hs[1][t] = base + c0;
        hs[2][t] = base + c0 + c1;
        hs[3][t] = base + c0 + c1 + c2;
    }
    __syncthreads();
    // pass 2: scatter via per-wave cursors (src/dst re-read is an L2 hit)
    for (int i = t; i < EPB / 4; i += 256) {
        int4 dv = d4[i];
        int4 sv = s4[i];
        int p;
        p = atomicAdd(&hd[w][dv.x >> 8], 1); edge_d[p] = ((dv.x & 255) << 16) | sv.x;
        p = atomicAdd(&hd[w][dv.y >> 8], 1); edge_d[p] = ((dv.y & 255) << 16) | sv.y;
        p = atomicAdd(&hd[w][dv.z >> 8], 1); edge_d[p] = ((dv.z & 255) << 16) | sv.z;
        p = atomicAdd(&hd[w][dv.w >> 8], 1); edge_d[p] = ((dv.w & 255) << 16) | sv.w;
        p = atomicAdd(&hs[w][sv.x >> 8], 1); edge_s[p] = (unsigned char)(sv.x & 255);
        p = atomicAdd(&hs[w][sv.y >> 8], 1); edge_s[p] = (unsigned char)(sv.y & 255);
        p = atomicAdd(&hs[w][sv.z >> 8], 1); edge_s[p] = (unsigned char)(sv.z & 255);
        p = atomicAdd(&hs[w][sv.w >> 8], 1); edge_s[p] = (unsigned char)(sv.w & 255);
    }
}

// ---- per-bucket CSR build -> ushort csr + meta{nd,ns,cnt} -------------------------
__global__ void bucket_build_kernel(const int* __restrict__ edge_d,
                                    const unsigned char* __restrict__ edge_s,
                                    const int* __restrict__ gseg,
                                    unsigned short* __restrict__ csr,
                                    float4* __restrict__ meta) {
    __shared__ int cur[256];
    __shared__ int hsm[256];
    int t = threadIdx.x;
    int bucket = blockIdx.x;
    cur[t] = 0;
    hsm[t] = 0;
    __syncthreads();
    int lend = gseg[bucket];           if (lend > SEGCAP) lend = SEGCAP;
    int lens = gseg[NBUCK + bucket];   if (lens > SEGCAP) lens = SEGCAP;
    int lo = bucket * SEGCAP;
    for (int i = lo + t; i < lo + lend; i += 256) {
        int pd = edge_d[i];
        int dlow = pd >> 16;
        int s = pd & 0xFFFF;
        int pos = atomicAdd(&cur[dlow], 1);
        if (pos < CAP)
            csr[(size_t)(bucket * 256 + dlow) * CAP + pos] = (unsigned short)s;
    }
    for (int i = lo + t; i < lo + lens; i += 256) {
        atomicAdd(&hsm[edge_s[i]], 1);
    }
    __syncthreads();
    int node = bucket * 256 + t;
    if (node < N_NODES) {
        int c = cur[t] < CAP ? cur[t] : CAP;
        float4 m;
        m.x = rsqrtf(fmaxf((float)c, 1.0f));         // norm_dst
        m.y = rsqrtf(fmaxf((float)hsm[t], 1.0f));    // norm_src
        m.z = __int_as_float(c);                     // cnt
        m.w = 0.f;
        meta[node] = m;
    }
}

// ------- y = bf16((x @ W1) * norm_src)  [N x 64]  (persistent: W1 staged once) -----
__global__ void gemm_y_kernel(const float* __restrict__ x,
                              const float4* __restrict__ meta,
                              const float* __restrict__ W,   // [F][F]
                              __hip_bfloat16* __restrict__ y) {
    __shared__ float sW[F * F];      // 16 KB
    __shared__ float srow[16][F];    // 4 KB
    int t = threadIdx.x;
    for (int i = t; i < F * F; i += 256) sW[i] = W[i];
    int j = t & 63;            // output feature
    int w = t >> 6;            // wave 0..3
    for (int tile = blockIdx.x; tile < N_NODES / 16; tile += GY_BLOCKS) {
        int base = tile * 16;
        __syncthreads();       // sW ready (iter 0); srow free of prior readers
        for (int r = w; r < 16; r += 4) srow[r][j] = x[(size_t)(base + r) * F + j];
        __syncthreads();
        float a0 = 0, a1 = 0, a2 = 0, a3 = 0;
#pragma unroll
        for (int k = 0; k < F; k++) {
            float wv = sW[k * F + j];
            a0 += srow[w * 4 + 0][k] * wv;
            a1 += srow[w * 4 + 1][k] * wv;
            a2 += srow[w * 4 + 2][k] * wv;
            a3 += srow[w * 4 + 3][k] * wv;
        }
        int n0 = base + w * 4;
        y[(size_t)(n0 + 0) * F + j] = __float2bfloat16(a0 * meta[n0 + 0].y);
        y[(size_t)(n0 + 1) * F + j] = __float2bfloat16(a1 * meta[n0 + 1].y);
        y[(size_t)(n0 + 2) * F + j] = __float2bfloat16(a2 * meta[n0 + 2].y);
        y[(size_t)(n0 + 3) * F + j] = __float2bfloat16(a3 * meta[n0 + 3].y);
    }
}

// -------- gather64 + fused W2 GEMV (v6 = R8-proven): ushort csr, 3 rounds + tail ---
__global__ void gather64_gemv_kernel(const __hip_bfloat16* __restrict__ y,
                                     const unsigned short* __restrict__ csr,
                                     const float4* __restrict__ meta,
                                     const float* __restrict__ b1,
                                     const float* __restrict__ W2,  // [F][C]
                                     __hip_bfloat16* __restrict__ gt) {  // [N][32]
    __shared__ float sW[F * C];       // 8 KB
    int t = threadIdx.x;
    for (int i = t; i < F * C; i += 256) sW[i] = W2[i];
    __syncthreads();                  // only barrier in the kernel
    int w    = t >> 6;
    int lane = t & 63;
    int g  = lane >> 3;               // edge group 0..7
    int fo = (lane & 7) * 8;          // feature offset (8 feats/lane)
    int j    = lane & 31;             // GEMV output class
    int half = lane >> 5;             // GEMV k-half
    const float4 b1a = *reinterpret_cast<const float4*>(b1 + fo);
    const float4 b1b = *reinterpret_cast<const float4*>(b1 + fo + 4);
    const unsigned short* ytab = reinterpret_cast<const unsigned short*>(y);
    const int STRIDE = G1_BLOCKS * 4;

    int node = blockIdx.x * 4 + w;
    float4 pm = meta[node];
    const unsigned short* prow = csr + (size_t)node * CAP;
    int pr0 = prow[g], pr1 = prow[8 + g], pr2 = prow[16 + g];

    while (node < N_NODES) {
        float nd = pm.x, ns = pm.y;
        int n = __float_as_int(pm.z);
        int r0 = pr0, r1 = pr1, r2 = pr2;
        int nxt = node + STRIDE;
        int pf = (nxt < N_NODES) ? nxt : node;   // clamp (harmless refetch)

        int ss0 = (g      < n) ? r0 : 0;  float m0 = (g      < n) ? 1.f : 0.f;
        int ss1 = (8  + g < n) ? r1 : 0;  float m1 = (8  + g < n) ? 1.f : 0.f;
        int ss2 = (16 + g < n) ? r2 : 0;  float m2 = (16 + g < n) ? 1.f : 0.f;

        const int4 v0 = *reinterpret_cast<const int4*>(ytab + (size_t)ss0 * F + fo);
        const int4 v1 = *reinterpret_cast<const int4*>(ytab + (size_t)ss1 * F + fo);
        const int4 v2 = *reinterpret_cast<const int4*>(ytab + (size_t)ss2 * F + fo);

        // prefetch next node's meta + row indices (overlaps y epoch)
        pm = meta[pf];
        const unsigned short* nrow = csr + (size_t)pf * CAP;
        pr0 = nrow[g]; pr1 = nrow[8 + g]; pr2 = nrow[16 + g];

        float a0, a1, a2, a3, a4, a5, a6, a7;
        a0 = m0 * bflo(v0.x); a1 = m0 * bfhi(v0.x);
        a2 = m0 * bflo(v0.y); a3 = m0 * bfhi(v0.y);
        a4 = m0 * bflo(v0.z); a5 = m0 * bfhi(v0.z);
        a6 = m0 * bflo(v0.w); a7 = m0 * bfhi(v0.w);

#define G1_ACC(vv, mm)                                                        \
        a0 = fmaf(mm, bflo(vv.x), a0); a1 = fmaf(mm, bfhi(vv.x), a1);         \
        a2 = fmaf(mm, bflo(vv.y), a2); a3 = fmaf(mm, bfhi(vv.y), a3);         \
        a4 = fmaf(mm, bflo(vv.z), a4); a5 = fmaf(mm, bfhi(vv.z), a5);         \
        a6 = fmaf(mm, bflo(vv.w), a6); a7 = fmaf(mm, bfhi(vv.w), a7);
        G1_ACC(v1, m1)
        G1_ACC(v2, m2)

        if (__builtin_expect(n > 24, 0)) {   // wave-uniform, ~2% of nodes
            const unsigned short* row = csr + (size_t)node * CAP;
            int r3 = row[24 + g], r4 = row[32 + g], r5 = row[40 + g];
            int ss3 = (24 + g < n) ? r3 : 0;  float m3 = (24 + g < n) ? 1.f : 0.f;
            int ss4 = (32 + g < n) ? r4 : 0;  float m4 = (32 + g < n) ? 1.f : 0.f;
            int ss5 = (40 + g < n) ? r5 : 0;  float m5 = (40 + g < n) ? 1.f : 0.f;
            const int4 v3 = *reinterpret_cast<const int4*>(ytab + (size_t)ss3 * F + fo);
            const int4 v4 = *reinterpret_cast<const int4*>(ytab + (size_t)ss4 * F + fo);
            const int4 v5 = *reinterpret_cast<const int4*>(ytab + (size_t)ss5 * F + fo);
            G1_ACC(v3, m3)
            G1_ACC(v4, m4)
            G1_ACC(v5, m5)
        }
#undef G1_ACC

        // butterfly over the 8 edge groups -> every lane holds full h[fo..fo+7]
#define G1_RED(mk)                                                           \
        a0 += __shfl_xor(a0, mk); a1 += __shfl_xor(a1, mk);                  \
        a2 += __shfl_xor(a2, mk); a3 += __shfl_xor(a3, mk);                  \
        a4 += __shfl_xor(a4, mk); a5 += __shfl_xor(a5, mk);                  \
        a6 += __shfl_xor(a6, mk); a7 += __shfl_xor(a7, mk);
        G1_RED(8)
        G1_RED(16)
        G1_RED(32)
#undef G1_RED

        float hh[8];
        hh[0] = fmaxf(fmaf(a0, nd, b1a.x), 0.f) * ns;
        hh[1] = fmaxf(fmaf(a1, nd, b1a.y), 0.f) * ns;
        hh[2] = fmaxf(fmaf(a2, nd, b1a.z), 0.f) * ns;
        hh[3] = fmaxf(fmaf(a3, nd, b1a.w), 0.f) * ns;
        hh[4] = fmaxf(fmaf(a4, nd, b1b.x), 0.f) * ns;
        hh[5] = fmaxf(fmaf(a5, nd, b1b.y), 0.f) * ns;
        hh[6] = fmaxf(fmaf(a6, nd, b1b.z), 0.f) * ns;
        hh[7] = fmaxf(fmaf(a7, nd, b1b.w), 0.f) * ns;

        // GEMV: o_j = sum_k h[kk] * W2[kk][j]; h[kk] lives at lane kk>>3, comp kk&7
        float o = 0.f;
#pragma unroll
        for (int k = 0; k < 32; k++) {
            float hv = __shfl(hh[k & 7], (half << 2) + (k >> 3));
            o = fmaf(hv, sW[(half * 32 + k) * C + j], o);
        }
        o += __shfl_down(o, 32);
        if (half == 0)
            __builtin_nontemporal_store(f2bf(o),
                reinterpret_cast<unsigned short*>(gt) + (size_t)node * C + j);
        node = nxt;
    }
}

// -------- gather_out (v6 = R8-proven): ushort csr, 3 rounds + tail -----------------
__global__ void gather_out_kernel(const __hip_bfloat16* __restrict__ gt,  // [N][32]
                                  const unsigned short* __restrict__ csr,
                                  const float4* __restrict__ meta,
                                  const float* __restrict__ b2,
                                  float* __restrict__ out) {
    int t = threadIdx.x;
    int w = t >> 6;
    int lane = t & 63;
    int g  = lane >> 3;                     // edge group 0..7
    int fo = (lane & 7) * 4;                // feature offset (4 feats/lane)
    const unsigned short* tab = reinterpret_cast<const unsigned short*>(gt);
    const float4 bb = *reinterpret_cast<const float4*>(b2 + fo);
    const int STRIDE = GOUT_BLOCKS * 4;

    int node = blockIdx.x * 4 + w;
    float4 pm = meta[node];
    const unsigned short* prow = csr + (size_t)node * CAP;
    int pr0 = prow[g], pr1 = prow[8 + g], pr2 = prow[16 + g];

    while (node < N_NODES) {
        float nd = pm.x;
        int n = __float_as_int(pm.z);
        int r0 = pr0, r1 = pr1, r2 = pr2;
        int nxt = node + STRIDE;
        int pf = (nxt < N_NODES) ? nxt : node;

        int ss0 = (g      < n) ? r0 : 0;  float m0 = (g      < n) ? 1.f : 0.f;
        int ss1 = (8  + g < n) ? r1 : 0;  float m1 = (8  + g < n) ? 1.f : 0.f;
        int ss2 = (16 + g < n) ? r2 : 0;  float m2 = (16 + g < n) ? 1.f : 0.f;

        const int2 v0 = *reinterpret_cast<const int2*>(tab + (size_t)ss0 * C + fo);
        const int2 v1 = *reinterpret_cast<const int2*>(tab + (size_t)ss1 * C + fo);
        const int2 v2 = *reinterpret_cast<const int2*>(tab + (size_t)ss2 * C + fo);

        pm = meta[pf];
        const unsigned short* nrow = csr + (size_t)pf * CAP;
        pr0 = nrow[g]; pr1 = nrow[8 + g]; pr2 = nrow[16 + g];

        float a0, a1, a2, a3;
        a0 = m0 * bflo(v0.x); a1 = m0 * bfhi(v0.x);
        a2 = m0 * bflo(v0.y); a3 = m0 * bfhi(v0.y);

#define G2_ACC(vv, mm)                                                        \
        a0 = fmaf(mm, bflo(vv.x), a0); a1 = fmaf(mm, bfhi(vv.x), a1);         \
        a2 = fmaf(mm, bflo(vv.y), a2); a3 = fmaf(mm, bfhi(vv.y), a3);
        G2_ACC(v1, m1)
        G2_ACC(v2, m2)

        if (__builtin_expect(n > 24, 0)) {   // wave-uniform, ~2% of nodes
            const unsigned short* row = csr + (size_t)node * CAP;
            int r3 = row[24 + g], r4 = row[32 + g], r5 = row[40 + g];
            int ss3 = (24 + g < n) ? r3 : 0;  float m3 = (24 + g < n) ? 1.f : 0.f;
            int ss4 = (32 + g < n) ? r4 : 0;  float m4 = (32 + g < n) ? 1.f : 0.f;
            int ss5 = (40 + g < n) ? r5 : 0;  float m5 = (40 + g < n) ? 1.f : 0.f;
            const int2 v3 = *reinterpret_cast<const int2*>(tab + (size_t)ss3 * C + fo);
            const int2 v4 = *reinterpret_cast<const int2*>(tab + (size_t)ss4 * C + fo);
            const int2 v5 = *reinterpret_cast<const int2*>(tab + (size_t)ss5 * C + fo);
            G2_ACC(v3, m3)
            G2_ACC(v4, m4)
            G2_ACC(v5, m5)
        }
#undef G2_ACC

        a0 += __shfl_xor(a0, 8);  a1 += __shfl_xor(a1, 8);
        a2 += __shfl_xor(a2, 8);  a3 += __shfl_xor(a3, 8);
        a0 += __shfl_xor(a0, 16); a1 += __shfl_xor(a1, 16);
        a2 += __shfl_xor(a2, 16); a3 += __shfl_xor(a3, 16);
        a0 += __shfl_xor(a0, 32); a1 += __shfl_xor(a1, 32);
        a2 += __shfl_xor(a2, 32); a3 += __shfl_xor(a3, 32);

        if (lane < 8) {
            float o0 = fmaf(a0, nd, bb.x);
            float o1 = fmaf(a1, nd, bb.y);
            float o2 = fmaf(a2, nd, bb.z);
            float o3 = fmaf(a3, nd, bb.w);
            unsigned long long p0 = ((unsigned long long)__float_as_uint(o0)) |
                                    ((unsigned long long)__float_as_uint(o1) << 32);
            unsigned long long p1 = ((unsigned long long)__float_as_uint(o2)) |
                                    ((unsigned long long)__float_as_uint(o3) << 32);
            unsigned long long* po = reinterpret_cast<unsigned long long*>(
                out + (size_t)node * C + fo);
            __builtin_nontemporal_store(p0, po);
            __builtin_nontemporal_store(p1, po + 1);
        }
        node = nxt;
    }
}

extern "C" void kernel_launch(void* const* d_in, const int* in_sizes, int n_in,
                              void* d_out, int out_size, void* d_ws, size_t ws_size,
                              hipStream_t stream) {
    const float* features = (const float*)d_in[0];   // [N, 64]
    const int*   src      = (const int*)d_in[1];     // [E]
    const int*   dst      = (const int*)d_in[2];     // [E]
    const float* W1       = (const float*)d_in[3];   // [64,64]
    const float* b1       = (const float*)d_in[4];   // [64]
    const float* W2       = (const float*)d_in[5];   // [64,32]
    const float* b2       = (const float*)d_in[6];   // [32]
    float* out = (float*)d_out;                      // [N, 32]

    // ---- workspace layout ----
    //   meta[N]float4 (0.8 MB) | csr[N*CAP]ushort (4.8 MB) | y[N*F]bf16 (6.4 MB) |
    //   gt[N*C]bf16 (3.2 MB)
    // aliases: edge_d (4.01 MB) + edge_s (0.98 MB) in y region (dead before gemm_y
    //          writes y); gseg[392] (1.6 KB) in gt region (dead after bucket_build).
    char* p = (char*)d_ws;
    float4* meta = (float4*)p;            p += (size_t)N_NODES * 16;       // 0.8 MB
    unsigned short* csr = (unsigned short*)p; p += (size_t)N_NODES * CAP * 2; // 4.8 MB
    __hip_bfloat16* y  = (__hip_bfloat16*)p;  p += (size_t)N_NODES * F * 2; // 6.4 MB
    __hip_bfloat16* gt = (__hip_bfloat16*)p;  /* 3.2 MB */

    int* edge_d = (int*)y;                                     // 4.01 MB
    unsigned char* edge_s = (unsigned char*)(edge_d + NBUCK * SEGCAP); // 0.98 MB
    int* gseg   = (int*)gt;                                    // 1.6 KB

    // 0) zero gseg cursors (tiny, graph-capture-safe)
    hipMemsetAsync(gseg, 0, (size_t)(2 * NBUCK) * 4, stream);

    // 1) graph build: fused count+reserve+scatter (per-wave), then CSR build
    part_fused_kernel<<<NPB, 256, 0, stream>>>(src, dst, gseg, edge_d, edge_s);
    bucket_build_kernel<<<NBUCK, 256, 0, stream>>>(edge_d, edge_s, gseg, csr, meta);

    // 2) layer 1 + fused W2 GEMV -> gt (3.2 MB, L2-resident)
    gemm_y_kernel<<<GY_BLOCKS, 256, 0, stream>>>(features, meta, W1, y);
    gather64_gemv_kernel<<<G1_BLOCKS, 256, 0, stream>>>(y, csr, meta, b1, W2, gt);

    // 3) layer 2: small-row gather + epilogue (pipelined, persistent)
    gather_out_kernel<<<GOUT_BLOCKS, 256, 0, stream>>>(gt, csr, meta, b2, out);
}

// Round 11
// 185.311 us; speedup vs baseline: 1.0415x; 1.0247x over previous
//
#include <hip/hip_runtime.h>
#include <hip/hip_bf16.h>

#define N_NODES 50000
#define N_EDGES 800000
#define F 64    // IN_FEATS == HIDDEN
#define C 32    // NUM_CLASSES
#define CAP 48  // fixed CSR row capacity; in-deg ~Poisson(16), max ~40

#define NPB   800    // partition blocks (3+ waves/SIMD)
#define EPB   1000   // edges per partition block (800*1000 == 800000)
#define NBUCK 196    // node buckets of 256 nodes
#define SEGCAP 5120  // per-bucket edge segment (mean 4096, sd 64 -> 16 sigma)

#define G1_BLOCKS   2048  // persistent blocks for gather64_gemv
#define GOUT_BLOCKS 2048  // persistent blocks for gather_out

static __device__ __forceinline__ float bflo(int u) {
    return __uint_as_float(((unsigned)u) << 16);
}
static __device__ __forceinline__ float bfhi(int u) {
    return __uint_as_float(((unsigned)u) & 0xffff0000u);
}
static __device__ __forceinline__ unsigned short f2bf(float f) {
    __hip_bfloat16 h = __float2bfloat16(f);
    return *reinterpret_cast<unsigned short*>(&h);
}

// ---- fused partition v3 (R10): per-wave histograms + cursors ----------------------
__global__ void part_fused_kernel(const int* __restrict__ src, const int* __restrict__ dst,
                                  int* __restrict__ gseg,        // [2*NBUCK], pre-zeroed
                                  int* __restrict__ edge_d, unsigned char* __restrict__ edge_s) {
    __shared__ int hd[4][NBUCK], hs[4][NBUCK];
    int t = threadIdx.x;
    int w = t >> 6;
    for (int i = t; i < 4 * NBUCK; i += 256) {
        (&hd[0][0])[i] = 0;
        (&hs[0][0])[i] = 0;
    }
    __syncthreads();
    int b0 = blockIdx.x * EPB;
    const int4* s4 = reinterpret_cast<const int4*>(src + b0);
    const int4* d4 = reinterpret_cast<const int4*>(dst + b0);
    for (int i = t; i < EPB / 4; i += 256) {
        int4 dv = d4[i];
        int4 sv = s4[i];
        atomicAdd(&hd[w][dv.x >> 8], 1); atomicAdd(&hd[w][dv.y >> 8], 1);
        atomicAdd(&hd[w][dv.z >> 8], 1); atomicAdd(&hd[w][dv.w >> 8], 1);
        atomicAdd(&hs[w][sv.x >> 8], 1); atomicAdd(&hs[w][sv.y >> 8], 1);
        atomicAdd(&hs[w][sv.z >> 8], 1); atomicAdd(&hs[w][sv.w >> 8], 1);
    }
    __syncthreads();
    if (t < NBUCK) {
        int c0 = hd[0][t], c1 = hd[1][t], c2 = hd[2][t], c3 = hd[3][t];
        int base = t * SEGCAP + atomicAdd(&gseg[t], c0 + c1 + c2 + c3);
        hd[0][t] = base;
        hd[1][t] = base + c0;
        hd[2][t] = base + c0 + c1;
        hd[3][t] = base + c0 + c1 + c2;
        c0 = hs[0][t]; c1 = hs[1][t]; c2 = hs[2][t]; c3 = hs[3][t];
        base = t * SEGCAP + atomicAdd(&gseg[NBUCK + t], c0 + c1 + c2 + c3);
        hs[0][t] = base;
        hs[1][t] = base + c0;
        hs[2][t] = base + c0 + c1;
        hs[3][t] = base + c0 + c1 + c2;
    }
    __syncthreads();
    for (int i = t; i < EPB / 4; i += 256) {
        int4 dv = d4[i];
        int4 sv = s4[i];
        int p;
        p = atomicAdd(&hd[w][dv.x >> 8], 1); edge_d[p] = ((dv.x & 255) << 16) | sv.x;
        p = atomicAdd(&hd[w][dv.y >> 8], 1); edge_d[p] = ((dv.y & 255) << 16) | sv.y;
        p = atomicAdd(&hd[w][dv.z >> 8], 1); edge_d[p] = ((dv.z & 255) << 16) | sv.z;
        p = atomicAdd(&hd[w][dv.w >> 8], 1); edge_d[p] = ((dv.w & 255) << 16) | sv.w;
        p = atomicAdd(&hs[w][sv.x >> 8], 1); edge_s[p] = (unsigned char)(sv.x & 255);
        p = atomicAdd(&hs[w][sv.y >> 8], 1); edge_s[p] = (unsigned char)(sv.y & 255);
        p = atomicAdd(&hs[w][sv.z >> 8], 1); edge_s[p] = (unsigned char)(sv.z & 255);
        p = atomicAdd(&hs[w][sv.w >> 8], 1); edge_s[p] = (unsigned char)(sv.w & 255);
    }
}

// ---- bucket build + FUSED layer-1 GEMM (1024 threads) -----------------------------
// v2: (a) 1024 threads -> CSR phase serial iterations 16->4, 4 waves/SIMD on the
// resident CU (was 1); (b) after meta, the SAME block computes y for its 256
// nodes (4 passes x 64 rows), W1 staged once, ns handed over via LDS. Replaces
// the separate gemm_y dispatch and its meta re-read.
__global__ void __launch_bounds__(1024)
bucket_build_kernel(const int* __restrict__ edge_d,
                    const unsigned char* __restrict__ edge_s,
                    const int* __restrict__ gseg,
                    const float* __restrict__ x,
                    const float* __restrict__ W,   // [F][F]
                    unsigned short* __restrict__ csr,
                    float4* __restrict__ meta,
                    __hip_bfloat16* __restrict__ y) {
    __shared__ int cur[256];
    __shared__ int hsm[256];
    __shared__ float nsb[256];
    __shared__ float sW[F * F];      // 16 KB
    __shared__ float srow[64][F];    // 16 KB
    int t = threadIdx.x;
    int bucket = blockIdx.x;
    if (t < 256) { cur[t] = 0; hsm[t] = 0; }
    for (int i = t; i < F * F; i += 1024) sW[i] = W[i];
    __syncthreads();
    int lend = gseg[bucket];           if (lend > SEGCAP) lend = SEGCAP;
    int lens = gseg[NBUCK + bucket];   if (lens > SEGCAP) lens = SEGCAP;
    int lo = bucket * SEGCAP;
    for (int i = lo + t; i < lo + lend; i += 1024) {
        int pd = edge_d[i];
        int dlow = pd >> 16;
        int s = pd & 0xFFFF;
        int pos = atomicAdd(&cur[dlow], 1);
        if (pos < CAP)
            csr[(size_t)(bucket * 256 + dlow) * CAP + pos] = (unsigned short)s;
    }
    for (int i = lo + t; i < lo + lens; i += 1024) {
        atomicAdd(&hsm[edge_s[i]], 1);
    }
    __syncthreads();
    if (t < 256) {
        int node = bucket * 256 + t;
        if (node < N_NODES) {
            int c = cur[t] < CAP ? cur[t] : CAP;
            float ns = rsqrtf(fmaxf((float)hsm[t], 1.0f));
            float4 m;
            m.x = rsqrtf(fmaxf((float)c, 1.0f));     // norm_dst
            m.y = ns;                                // norm_src
            m.z = __int_as_float(c);                 // cnt
            m.w = 0.f;
            meta[node] = m;
            nsb[t] = ns;
        } else {
            nsb[t] = 0.f;
        }
    }
    __syncthreads();
    // ---- fused layer-1 GEMM: y[n][j] = bf16((x[n] . W[:,j]) * ns[n]) ----
    int w = t >> 6;            // wave 0..15
    int j = t & 63;            // output feature
    for (int pass = 0; pass < 4; pass++) {
        int base = bucket * 256 + pass * 64;
        // stage 64 rows of x (zero-padded past N)
        for (int idx = t; idx < 64 * F; idx += 1024) {
            int r = idx >> 6;
            int nn = base + r;
            srow[r][idx & 63] = (nn < N_NODES) ? x[(size_t)nn * F + (idx & 63)] : 0.f;
        }
        __syncthreads();
        float a0 = 0, a1 = 0, a2 = 0, a3 = 0;
#pragma unroll
        for (int k = 0; k < F; k++) {
            float wv = sW[k * F + j];
            a0 += srow[w * 4 + 0][k] * wv;
            a1 += srow[w * 4 + 1][k] * wv;
            a2 += srow[w * 4 + 2][k] * wv;
            a3 += srow[w * 4 + 3][k] * wv;
        }
        int n0 = base + w * 4;
        int l0 = pass * 64 + w * 4;
        if (n0 + 3 < N_NODES) {
            y[(size_t)(n0 + 0) * F + j] = __float2bfloat16(a0 * nsb[l0 + 0]);
            y[(size_t)(n0 + 1) * F + j] = __float2bfloat16(a1 * nsb[l0 + 1]);
            y[(size_t)(n0 + 2) * F + j] = __float2bfloat16(a2 * nsb[l0 + 2]);
            y[(size_t)(n0 + 3) * F + j] = __float2bfloat16(a3 * nsb[l0 + 3]);
        } else {
            if (n0 + 0 < N_NODES) y[(size_t)(n0 + 0) * F + j] = __float2bfloat16(a0 * nsb[l0 + 0]);
            if (n0 + 1 < N_NODES) y[(size_t)(n0 + 1) * F + j] = __float2bfloat16(a1 * nsb[l0 + 1]);
            if (n0 + 2 < N_NODES) y[(size_t)(n0 + 2) * F + j] = __float2bfloat16(a2 * nsb[l0 + 2]);
            if (n0 + 3 < N_NODES) y[(size_t)(n0 + 3) * F + j] = __float2bfloat16(a3 * nsb[l0 + 3]);
        }
        __syncthreads();       // srow reused next pass
    }
}

// -------- gather64 + fused W2 GEMV (v6 = R8-proven): ushort csr, 3 rounds + tail ---
__global__ void gather64_gemv_kernel(const __hip_bfloat16* __restrict__ y,
                                     const unsigned short* __restrict__ csr,
                                     const float4* __restrict__ meta,
                                     const float* __restrict__ b1,
                                     const float* __restrict__ W2,  // [F][C]
                                     __hip_bfloat16* __restrict__ gt) {  // [N][32]
    __shared__ float sW[F * C];       // 8 KB
    int t = threadIdx.x;
    for (int i = t; i < F * C; i += 256) sW[i] = W2[i];
    __syncthreads();                  // only barrier in the kernel
    int w    = t >> 6;
    int lane = t & 63;
    int g  = lane >> 3;               // edge group 0..7
    int fo = (lane & 7) * 8;          // feature offset (8 feats/lane)
    int j    = lane & 31;             // GEMV output class
    int half = lane >> 5;             // GEMV k-half
    const float4 b1a = *reinterpret_cast<const float4*>(b1 + fo);
    const float4 b1b = *reinterpret_cast<const float4*>(b1 + fo + 4);
    const unsigned short* ytab = reinterpret_cast<const unsigned short*>(y);
    const int STRIDE = G1_BLOCKS * 4;

    int node = blockIdx.x * 4 + w;
    float4 pm = meta[node];
    const unsigned short* prow = csr + (size_t)node * CAP;
    int pr0 = prow[g], pr1 = prow[8 + g], pr2 = prow[16 + g];

    while (node < N_NODES) {
        float nd = pm.x, ns = pm.y;
        int n = __float_as_int(pm.z);
        int r0 = pr0, r1 = pr1, r2 = pr2;
        int nxt = node + STRIDE;
        int pf = (nxt < N_NODES) ? nxt : node;   // clamp (harmless refetch)

        int ss0 = (g      < n) ? r0 : 0;  float m0 = (g      < n) ? 1.f : 0.f;
        int ss1 = (8  + g < n) ? r1 : 0;  float m1 = (8  + g < n) ? 1.f : 0.f;
        int ss2 = (16 + g < n) ? r2 : 0;  float m2 = (16 + g < n) ? 1.f : 0.f;

        const int4 v0 = *reinterpret_cast<const int4*>(ytab + (size_t)ss0 * F + fo);
        const int4 v1 = *reinterpret_cast<const int4*>(ytab + (size_t)ss1 * F + fo);
        const int4 v2 = *reinterpret_cast<const int4*>(ytab + (size_t)ss2 * F + fo);

        // prefetch next node's meta + row indices (overlaps y epoch)
        pm = meta[pf];
        const unsigned short* nrow = csr + (size_t)pf * CAP;
        pr0 = nrow[g]; pr1 = nrow[8 + g]; pr2 = nrow[16 + g];

        float a0, a1, a2, a3, a4, a5, a6, a7;
        a0 = m0 * bflo(v0.x); a1 = m0 * bfhi(v0.x);
        a2 = m0 * bflo(v0.y); a3 = m0 * bfhi(v0.y);
        a4 = m0 * bflo(v0.z); a5 = m0 * bfhi(v0.z);
        a6 = m0 * bflo(v0.w); a7 = m0 * bfhi(v0.w);

#define G1_ACC(vv, mm)                                                        \
        a0 = fmaf(mm, bflo(vv.x), a0); a1 = fmaf(mm, bfhi(vv.x), a1);         \
        a2 = fmaf(mm, bflo(vv.y), a2); a3 = fmaf(mm, bfhi(vv.y), a3);         \
        a4 = fmaf(mm, bflo(vv.z), a4); a5 = fmaf(mm, bfhi(vv.z), a5);         \
        a6 = fmaf(mm, bflo(vv.w), a6); a7 = fmaf(mm, bfhi(vv.w), a7);
        G1_ACC(v1, m1)
        G1_ACC(v2, m2)

        if (__builtin_expect(n > 24, 0)) {   // wave-uniform, ~2% of nodes
            const unsigned short* row = csr + (size_t)node * CAP;
            int r3 = row[24 + g], r4 = row[32 + g], r5 = row[40 + g];
            int ss3 = (24 + g < n) ? r3 : 0;  float m3 = (24 + g < n) ? 1.f : 0.f;
            int ss4 = (32 + g < n) ? r4 : 0;  float m4 = (32 + g < n) ? 1.f : 0.f;
            int ss5 = (40 + g < n) ? r5 : 0;  float m5 = (40 + g < n) ? 1.f : 0.f;
            const int4 v3 = *reinterpret_cast<const int4*>(ytab + (size_t)ss3 * F + fo);
            const int4 v4 = *reinterpret_cast<const int4*>(ytab + (size_t)ss4 * F + fo);
            const int4 v5 = *reinterpret_cast<const int4*>(ytab + (size_t)ss5 * F + fo);
            G1_ACC(v3, m3)
            G1_ACC(v4, m4)
            G1_ACC(v5, m5)
        }
#undef G1_ACC

        // butterfly over the 8 edge groups -> every lane holds full h[fo..fo+7]
#define G1_RED(mk)                                                           \
        a0 += __shfl_xor(a0, mk); a1 += __shfl_xor(a1, mk);                  \
        a2 += __shfl_xor(a2, mk); a3 += __shfl_xor(a3, mk);                  \
        a4 += __shfl_xor(a4, mk); a5 += __shfl_xor(a5, mk);                  \
        a6 += __shfl_xor(a6, mk); a7 += __shfl_xor(a7, mk);
        G1_RED(8)
        G1_RED(16)
        G1_RED(32)
#undef G1_RED

        float hh[8];
        hh[0] = fmaxf(fmaf(a0, nd, b1a.x), 0.f) * ns;
        hh[1] = fmaxf(fmaf(a1, nd, b1a.y), 0.f) * ns;
        hh[2] = fmaxf(fmaf(a2, nd, b1a.z), 0.f) * ns;
        hh[3] = fmaxf(fmaf(a3, nd, b1a.w), 0.f) * ns;
        hh[4] = fmaxf(fmaf(a4, nd, b1b.x), 0.f) * ns;
        hh[5] = fmaxf(fmaf(a5, nd, b1b.y), 0.f) * ns;
        hh[6] = fmaxf(fmaf(a6, nd, b1b.z), 0.f) * ns;
        hh[7] = fmaxf(fmaf(a7, nd, b1b.w), 0.f) * ns;

        // GEMV: o_j = sum_k h[kk] * W2[kk][j]; h[kk] lives at lane kk>>3, comp kk&7
        float o = 0.f;
#pragma unroll
        for (int k = 0; k < 32; k++) {
            float hv = __shfl(hh[k & 7], (half << 2) + (k >> 3));
            o = fmaf(hv, sW[(half * 32 + k) * C + j], o);
        }
        o += __shfl_down(o, 32);
        if (half == 0)
            __builtin_nontemporal_store(f2bf(o),
                reinterpret_cast<unsigned short*>(gt) + (size_t)node * C + j);
        node = nxt;
    }
}

// -------- gather_out (v6 = R8-proven): ushort csr, 3 rounds + tail -----------------
__global__ void gather_out_kernel(const __hip_bfloat16* __restrict__ gt,  // [N][32]
                                  const unsigned short* __restrict__ csr,
                                  const float4* __restrict__ meta,
                                  const float* __restrict__ b2,
                                  float* __restrict__ out) {
    int t = threadIdx.x;
    int w = t >> 6;
    int lane = t & 63;
    int g  = lane >> 3;                     // edge group 0..7
    int fo = (lane & 7) * 4;                // feature offset (4 feats/lane)
    const unsigned short* tab = reinterpret_cast<const unsigned short*>(gt);
    const float4 bb = *reinterpret_cast<const float4*>(b2 + fo);
    const int STRIDE = GOUT_BLOCKS * 4;

    int node = blockIdx.x * 4 + w;
    float4 pm = meta[node];
    const unsigned short* prow = csr + (size_t)node * CAP;
    int pr0 = prow[g], pr1 = prow[8 + g], pr2 = prow[16 + g];

    while (node < N_NODES) {
        float nd = pm.x;
        int n = __float_as_int(pm.z);
        int r0 = pr0, r1 = pr1, r2 = pr2;
        int nxt = node + STRIDE;
        int pf = (nxt < N_NODES) ? nxt : node;

        int ss0 = (g      < n) ? r0 : 0;  float m0 = (g      < n) ? 1.f : 0.f;
        int ss1 = (8  + g < n) ? r1 : 0;  float m1 = (8  + g < n) ? 1.f : 0.f;
        int ss2 = (16 + g < n) ? r2 : 0;  float m2 = (16 + g < n) ? 1.f : 0.f;

        const int2 v0 = *reinterpret_cast<const int2*>(tab + (size_t)ss0 * C + fo);
        const int2 v1 = *reinterpret_cast<const int2*>(tab + (size_t)ss1 * C + fo);
        const int2 v2 = *reinterpret_cast<const int2*>(tab + (size_t)ss2 * C + fo);

        pm = meta[pf];
        const unsigned short* nrow = csr + (size_t)pf * CAP;
        pr0 = nrow[g]; pr1 = nrow[8 + g]; pr2 = nrow[16 + g];

        float a0, a1, a2, a3;
        a0 = m0 * bflo(v0.x); a1 = m0 * bfhi(v0.x);
        a2 = m0 * bflo(v0.y); a3 = m0 * bfhi(v0.y);

#define G2_ACC(vv, mm)                                                        \
        a0 = fmaf(mm, bflo(vv.x), a0); a1 = fmaf(mm, bfhi(vv.x), a1);         \
        a2 = fmaf(mm, bflo(vv.y), a2); a3 = fmaf(mm, bfhi(vv.y), a3);
        G2_ACC(v1, m1)
        G2_ACC(v2, m2)

        if (__builtin_expect(n > 24, 0)) {   // wave-uniform, ~2% of nodes
            const unsigned short* row = csr + (size_t)node * CAP;
            int r3 = row[24 + g], r4 = row[32 + g], r5 = row[40 + g];
            int ss3 = (24 + g < n) ? r3 : 0;  float m3 = (24 + g < n) ? 1.f : 0.f;
            int ss4 = (32 + g < n) ? r4 : 0;  float m4 = (32 + g < n) ? 1.f : 0.f;
            int ss5 = (40 + g < n) ? r5 : 0;  float m5 = (40 + g < n) ? 1.f : 0.f;
            const int2 v3 = *reinterpret_cast<const int2*>(tab + (size_t)ss3 * C + fo);
            const int2 v4 = *reinterpret_cast<const int2*>(tab + (size_t)ss4 * C + fo);
            const int2 v5 = *reinterpret_cast<const int2*>(tab + (size_t)ss5 * C + fo);
            G2_ACC(v3, m3)
            G2_ACC(v4, m4)
            G2_ACC(v5, m5)
        }
#undef G2_ACC

        a0 += __shfl_xor(a0, 8);  a1 += __shfl_xor(a1, 8);
        a2 += __shfl_xor(a2, 8);  a3 += __shfl_xor(a3, 8);
        a0 += __shfl_xor(a0, 16); a1 += __shfl_xor(a1, 16);
        a2 += __shfl_xor(a2, 16); a3 += __shfl_xor(a3, 16);
        a0 += __shfl_xor(a0, 32); a1 += __shfl_xor(a1, 32);
        a2 += __shfl_xor(a2, 32); a3 += __shfl_xor(a3, 32);

        if (lane < 8) {
            float o0 = fmaf(a0, nd, bb.x);
            float o1 = fmaf(a1, nd, bb.y);
            float o2 = fmaf(a2, nd, bb.z);
            float o3 = fmaf(a3, nd, bb.w);
            unsigned long long p0 = ((unsigned long long)__float_as_uint(o0)) |
                                    ((unsigned long long)__float_as_uint(o1) << 32);
            unsigned long long p1 = ((unsigned long long)__float_as_uint(o2)) |
                                    ((unsigned long long)__float_as_uint(o3) << 32);
            unsigned long long* po = reinterpret_cast<unsigned long long*>(
                out + (size_t)node * C + fo);
            __builtin_nontemporal_store(p0, po);
            __builtin_nontemporal_store(p1, po + 1);
        }
        node = nxt;
    }
}

extern "C" void kernel_launch(void* const* d_in, const int* in_sizes, int n_in,
                              void* d_out, int out_size, void* d_ws, size_t ws_size,
                              hipStream_t stream) {
    const float* features = (const float*)d_in[0];   // [N, 64]
    const int*   src      = (const int*)d_in[1];     // [E]
    const int*   dst      = (const int*)d_in[2];     // [E]
    const float* W1       = (const float*)d_in[3];   // [64,64]
    const float* b1       = (const float*)d_in[4];   // [64]
    const float* W2       = (const float*)d_in[5];   // [64,32]
    const float* b2       = (const float*)d_in[6];   // [32]
    float* out = (float*)d_out;                      // [N, 32]

    // ---- workspace layout ----
    //   meta[N]float4 (0.8 MB) | csr[N*CAP]ushort (4.8 MB) | y[N*F]bf16 (6.4 MB) |
    //   gt[N*C]bf16 (3.2 MB)
    // aliases: edge_d (4.01 MB) + edge_s (0.98 MB) in y region (dead before the
    //          fused build kernel writes y -- NOTE: build reads edge_d fully
    //          before its gemm phase writes y for the same bucket's nodes; y
    //          writes for bucket b land at [b*256*128 B], edge reads at
    //          [b*SEGCAP*4 B] -- overlapping regions, but each block reads its
    //          edges into registers/LDS before writing y? NOT true across
    //          blocks. So edge_d must NOT alias y here. Moved edge_d/edge_s
    //          AFTER gt instead (dedicated 5 MB).
    char* p = (char*)d_ws;
    float4* meta = (float4*)p;            p += (size_t)N_NODES * 16;       // 0.8 MB
    unsigned short* csr = (unsigned short*)p; p += (size_t)N_NODES * CAP * 2; // 4.8 MB
    __hip_bfloat16* y  = (__hip_bfloat16*)p;  p += (size_t)N_NODES * F * 2; // 6.4 MB
    __hip_bfloat16* gt = (__hip_bfloat16*)p;  p += (size_t)N_NODES * C * 2; // 3.2 MB
    int* edge_d = (int*)p;                p += (size_t)NBUCK * SEGCAP * 4;  // 4.01 MB
    unsigned char* edge_s = (unsigned char*)p; p += (size_t)NBUCK * SEGCAP; // 0.98 MB
    int* gseg = (int*)p;                                                    // 1.6 KB

    // 0) zero gseg cursors (tiny, graph-capture-safe)
    hipMemsetAsync(gseg, 0, (size_t)(2 * NBUCK) * 4, stream);

    // 1) graph build: fused count+reserve+scatter, then CSR build + layer-1 GEMM
    part_fused_kernel<<<NPB, 256, 0, stream>>>(src, dst, gseg, edge_d, edge_s);
    bucket_build_kernel<<<NBUCK, 1024, 0, stream>>>(edge_d, edge_s, gseg,
                                                    features, W1, csr, meta, y);

    // 2) layer-1 gather + fused W2 GEMV -> gt (3.2 MB, L2-resident)
    gather64_gemv_kernel<<<G1_BLOCKS, 256, 0, stream>>>(y, csr, meta, b1, W2, gt);

    // 3) layer 2: small-row gather + epilogue (pipelined, persistent)
    gather_out_kernel<<<GOUT_BLOCKS, 256, 0, stream>>>(gt, csr, meta, b2, out);
}